// Round 2
// baseline (2633.978 us; speedup 1.0000x reference)
//
#include <hip/hip_runtime.h>

// SIRLayer inference, MI355X.
// Counting-sort points by voxel so all voxel-max traffic is L2-local:
//   hist -> scan -> permute  (perm[j] = point id in voxel order, voxs[j] = voxel)
//   sir_k1<false> : gate + vfe0, streaming, p0 -> d_out (no scatter)
//   sir_kmax      : voxel max over p0 in sorted order (L2-hot filtered atomics)
//   sir_k2<true>  : vfe1 + shortcut in sorted order, in-place on d_out
//                   (perm is a bijection -> each block owns its row set)
// Fallback (ws too small): round-0 behavior: sir_k1<true> + sir_k2<false>.
//
// ws layout: [0,16MB) vmax u32[V*64] | +256KB cnt/cursor u32[V]
//            | +4*npts perm u32 | +4*npts voxs u32

#define VVOX 65536

// ---------------------------------------------------------------------------
__global__ void __launch_bounds__(256)
sir_hist(const int* __restrict__ coors, unsigned int* __restrict__ cnt, int npts)
{
    const int p = blockIdx.x * 256 + threadIdx.x;
    if (p < npts) atomicAdd(&cnt[coors[p]], 1u);
}

// in-place exclusive prefix sum over cnt[VVOX], single block of 1024 threads
__global__ void __launch_bounds__(1024)
sir_scan(unsigned int* __restrict__ cnt)
{
    __shared__ unsigned int s[1024];
    const int t = threadIdx.x;
    unsigned int sum = 0;
    for (int i = 0; i < 64; ++i) sum += cnt[t * 64 + i];
    s[t] = sum;
    __syncthreads();
    for (int off = 1; off < 1024; off <<= 1) {
        unsigned int v = (t >= off) ? s[t - off] : 0u;
        __syncthreads();
        s[t] += v;
        __syncthreads();
    }
    unsigned int run = s[t] - sum;   // exclusive prefix of this thread's chunk
    for (int i = 0; i < 64; ++i) {
        const unsigned int c = cnt[t * 64 + i];
        cnt[t * 64 + i] = run;
        run += c;
    }
}

__global__ void __launch_bounds__(256)
sir_permute(const int* __restrict__ coors, unsigned int* __restrict__ cursor,
            unsigned int* __restrict__ perm, unsigned int* __restrict__ voxs,
            int npts)
{
    const int p = blockIdx.x * 256 + threadIdx.x;
    if (p >= npts) return;
    const int vox = coors[p];
    const unsigned int j = atomicAdd(&cursor[vox], 1u);
    perm[j] = (unsigned int)p;
    voxs[j] = (unsigned int)vox;
}

// ---------------------------------------------------------------------------
// K1: gate MLP + vfe0, thread per point. SCATTER=false -> stream p0 only.
// ---------------------------------------------------------------------------
template <bool SCATTER>
__global__ void __launch_bounds__(256)
sir_k1(const float* __restrict__ xyz,
       const float* __restrict__ pfeat,
       const float* __restrict__ fclu,
       const int* __restrict__ coors,
       const float* __restrict__ rw0,
       const float* __restrict__ rg0,
       const float* __restrict__ rb0,
       const float* __restrict__ rw1,
       const float* __restrict__ rg1,
       const float* __restrict__ rb1,
       const float* __restrict__ vw0,
       const float* __restrict__ vg0,
       const float* __restrict__ vb0,
       unsigned int* __restrict__ vmax,   // used only if SCATTER
       float* __restrict__ p0out,         // d_out, [N,64]
       int npts)
{
    __shared__ float s_w0[48];    // rel_w0 [i*16+j] * g0[j]
    __shared__ float s_b0[16];
    __shared__ float s_w1t[1024]; // [k*16+j] = w1[j][k]*g1[k]
    __shared__ float s_b1[64];
    __shared__ float s_vw0[4096]; // vw0[k*64+c] * vg0[c]
    __shared__ float s_vb0[64];

    const int t = threadIdx.x;
    if (t < 48) s_w0[t] = rw0[t] * rg0[t & 15];
    if (t < 16) s_b0[t] = rb0[t];
    for (int i = t; i < 1024; i += 256) {
        int k = i >> 4, j = i & 15;
        s_w1t[i] = rw1[j * 64 + k] * rg1[k];
    }
    if (t < 64) s_b1[t] = rb1[t];
    for (int i = t; i < 4096; i += 256) s_vw0[i] = vw0[i] * vg0[i & 63];
    if (t < 64) s_vb0[t] = vb0[t];
    __syncthreads();

    const int pt = blockIdx.x * 256 + t;
    if (pt >= npts) return;

    const float* cr = fclu + (size_t)pt * 3;
    const float c0 = cr[0], c1 = cr[1], c2 = cr[2];
    float h[16];
    #pragma unroll
    for (int j = 0; j < 16; ++j) {
        float v = s_b0[j];
        v = fmaf(c0, s_w0[j], v);
        v = fmaf(c1, s_w0[16 + j], v);
        v = fmaf(c2, s_w0[32 + j], v);
        h[j] = fmaxf(v, 0.f);
    }

    float acc[64];
    #pragma unroll
    for (int c = 0; c < 64; ++c) acc[c] = s_vb0[c];

    const float* xr = xyz + (size_t)pt * 3;
    const float* fr = pfeat + (size_t)pt * 61;

    // gate_k = relu(h . w1[:,k] + b1_k); acc[c] += (f_k * gate_k) * vw0[k][c]
    for (int k = 0; k < 64; ++k) {
        const float* w1k = s_w1t + k * 16;
        float g0 = s_b1[k], g1 = 0.f, g2 = 0.f, g3 = 0.f;
        #pragma unroll
        for (int j = 0; j < 4; ++j) {
            g0 = fmaf(h[j],      w1k[j],      g0);
            g1 = fmaf(h[4 + j],  w1k[4 + j],  g1);
            g2 = fmaf(h[8 + j],  w1k[8 + j],  g2);
            g3 = fmaf(h[12 + j], w1k[12 + j], g3);
        }
        const float g = fmaxf((g0 + g1) + (g2 + g3), 0.f);
        const float fk = (k < 3) ? xr[k] : fr[k - 3];   // lazy f load: saves ~60 VGPR
        const float gk = fk * g;
        const float* wk = s_vw0 + k * 64;
        #pragma unroll
        for (int c = 0; c < 64; ++c) acc[c] = fmaf(gk, wk[c], acc[c]);
    }

    float4* orow = reinterpret_cast<float4*>(p0out + (size_t)pt * 64);
    if (SCATTER) {
        const int vox = coors[pt];
        unsigned int* vrow = vmax + (size_t)vox * 64;
        const uint4* vrow4 = reinterpret_cast<const uint4*>(vrow);
        #pragma unroll
        for (int q = 0; q < 16; ++q) {
            const uint4 cur = vrow4[q];
            float4 u;
            u.x = fmaxf(acc[q * 4 + 0], 0.f);
            u.y = fmaxf(acc[q * 4 + 1], 0.f);
            u.z = fmaxf(acc[q * 4 + 2], 0.f);
            u.w = fmaxf(acc[q * 4 + 3], 0.f);
            orow[q] = u;
            if (__float_as_uint(u.x) > cur.x) atomicMax(vrow + q * 4 + 0, __float_as_uint(u.x));
            if (__float_as_uint(u.y) > cur.y) atomicMax(vrow + q * 4 + 1, __float_as_uint(u.y));
            if (__float_as_uint(u.z) > cur.z) atomicMax(vrow + q * 4 + 2, __float_as_uint(u.z));
            if (__float_as_uint(u.w) > cur.w) atomicMax(vrow + q * 4 + 3, __float_as_uint(u.w));
        }
    } else {
        #pragma unroll
        for (int q = 0; q < 16; ++q) {
            float4 u;
            u.x = fmaxf(acc[q * 4 + 0], 0.f);
            u.y = fmaxf(acc[q * 4 + 1], 0.f);
            u.z = fmaxf(acc[q * 4 + 2], 0.f);
            u.w = fmaxf(acc[q * 4 + 3], 0.f);
            orow[q] = u;
        }
    }
}

// ---------------------------------------------------------------------------
// Kmax: voxel max over p0, points visited in voxel-sorted order.
// p0 >= 0 (post-relu) so fp32 max == uint max on bit patterns.
// ---------------------------------------------------------------------------
__global__ void __launch_bounds__(256)
sir_kmax(const float* __restrict__ p0,
         const unsigned int* __restrict__ perm,
         const unsigned int* __restrict__ voxs,
         unsigned int* __restrict__ vmax, int npts)
{
    const int j = blockIdx.x * 256 + threadIdx.x;
    if (j >= npts) return;
    const unsigned int p = perm[j];
    const unsigned int vox = voxs[j];
    const uint4* row = reinterpret_cast<const uint4*>(p0 + (size_t)p * 64);
    unsigned int* vrow = vmax + (size_t)vox * 64;
    const uint4* vrow4 = reinterpret_cast<const uint4*>(vrow);
    #pragma unroll
    for (int q = 0; q < 16; ++q) {
        const uint4 pv = row[q];
        const uint4 cur = vrow4[q];   // stale-read filter; monotone cells
        if (pv.x > cur.x) atomicMax(vrow + q * 4 + 0, pv.x);
        if (pv.y > cur.y) atomicMax(vrow + q * 4 + 1, pv.y);
        if (pv.z > cur.z) atomicMax(vrow + q * 4 + 2, pv.z);
        if (pv.w > cur.w) atomicMax(vrow + q * 4 + 3, pv.w);
    }
}

// ---------------------------------------------------------------------------
// K2: p1 = relu(concat(p0, v0[vox]) @ w1s + b1s) + concat(xyz, pfeat)
// SORTED: rows selected via perm (bijection -> in-place safe per block),
//         voxel rows arrive in sorted order -> L2-hot gather.
// ---------------------------------------------------------------------------
template <bool SORTED>
__global__ void __launch_bounds__(256)
sir_k2(const float* __restrict__ xyz,
       const float* __restrict__ pfeat,
       const int* __restrict__ coors,
       const unsigned int* __restrict__ perm,
       const unsigned int* __restrict__ voxs,
       const float* __restrict__ vw1,
       const float* __restrict__ vg1,
       const float* __restrict__ vb1,
       const float* __restrict__ vmaxf,   // [V*64] fp32
       float* __restrict__ io,            // d_out: in p0, out result
       int npts)
{
    __shared__ float s_w[8192];  // vw1[k*64+c] * vg1[c], k<128
    __shared__ float s_b[64];
    const int t = threadIdx.x;
    for (int i = t; i < 8192; i += 256) s_w[i] = vw1[i] * vg1[i & 63];
    if (t < 64) s_b[t] = vb1[t];
    __syncthreads();

    const int cg = t & 3;
    const int ps = t >> 2;
    const int base = blockIdx.x * 256;

    int p[4]; bool ok[4];
    const float4* prow[4];
    const float4* vrow[4];
    #pragma unroll
    for (int i = 0; i < 4; ++i) {
        const int idx = base + ps + 64 * i;
        ok[i] = idx < npts;
        int pc, vox;
        if (SORTED) {
            pc  = ok[i] ? (int)perm[idx] : 0;
            vox = ok[i] ? (int)voxs[idx] : 0;
        } else {
            pc  = ok[i] ? idx : 0;
            vox = coors[pc];
        }
        p[i] = pc;
        prow[i] = reinterpret_cast<const float4*>(io + (size_t)pc * 64);
        vrow[i] = reinterpret_cast<const float4*>(vmaxf + (size_t)vox * 64);
    }

    float acc[4][16];
    #pragma unroll
    for (int i = 0; i < 4; ++i)
        #pragma unroll
        for (int c = 0; c < 16; ++c) acc[i][c] = s_b[cg * 16 + c];

    float4 gv[4], gvn[4];

    // ---- part 1: p0 rows @ w[0:64] ----
    #pragma unroll
    for (int i = 0; i < 4; ++i) gv[i] = prow[i][0];
    for (int k4 = 0; k4 < 16; ++k4) {
        const int k4n = (k4 + 1) & 15;
        #pragma unroll
        for (int i = 0; i < 4; ++i) gvn[i] = prow[i][k4n];
        const float* wb = s_w + k4 * 256 + cg * 16;
        #pragma unroll
        for (int kk = 0; kk < 4; ++kk) {
            const float* wr = wb + kk * 64;
            #pragma unroll
            for (int i = 0; i < 4; ++i) {
                const float ga[4] = { gv[i].x, gv[i].y, gv[i].z, gv[i].w };
                const float gk = ga[kk];
                #pragma unroll
                for (int c = 0; c < 16; ++c)
                    acc[i][c] = fmaf(gk, wr[c], acc[i][c]);
            }
        }
        #pragma unroll
        for (int i = 0; i < 4; ++i) gv[i] = gvn[i];
    }

    // ---- part 2: gathered voxel rows @ w[64:128] ----
    #pragma unroll
    for (int i = 0; i < 4; ++i) gv[i] = vrow[i][0];
    for (int k4 = 0; k4 < 16; ++k4) {
        const int k4n = (k4 + 1) & 15;
        #pragma unroll
        for (int i = 0; i < 4; ++i) gvn[i] = vrow[i][k4n];
        const float* wb = s_w + 4096 + k4 * 256 + cg * 16;
        #pragma unroll
        for (int kk = 0; kk < 4; ++kk) {
            const float* wr = wb + kk * 64;
            #pragma unroll
            for (int i = 0; i < 4; ++i) {
                const float ga[4] = { gv[i].x, gv[i].y, gv[i].z, gv[i].w };
                const float gk = ga[kk];
                #pragma unroll
                for (int c = 0; c < 16; ++c)
                    acc[i][c] = fmaf(gk, wr[c], acc[i][c]);
            }
        }
        #pragma unroll
        for (int i = 0; i < 4; ++i) gv[i] = gvn[i];
    }

    // all reads of this block's p0 rows complete before in-place overwrite
    __syncthreads();

    #pragma unroll
    for (int i = 0; i < 4; ++i) {
        if (!ok[i]) continue;
        const float* xr = xyz + (size_t)p[i] * 3;
        const float* fr = pfeat + (size_t)p[i] * 61;
        float4* orow = reinterpret_cast<float4*>(io + (size_t)p[i] * 64 + cg * 16);
        #pragma unroll
        for (int q = 0; q < 4; ++q) {
            const int c = cg * 16 + q * 4;
            const float s0 = (c + 0 < 3) ? xr[c + 0] : fr[c - 3];
            const float s1 = (c + 1 < 3) ? xr[c + 1] : fr[c - 2];
            const float s2 = (c + 2 < 3) ? xr[c + 2] : fr[c - 1];
            const float s3 = (c + 3 < 3) ? xr[c + 3] : fr[c + 0];
            float4 u;
            u.x = fmaxf(acc[i][q * 4 + 0], 0.f) + s0;
            u.y = fmaxf(acc[i][q * 4 + 1], 0.f) + s1;
            u.z = fmaxf(acc[i][q * 4 + 2], 0.f) + s2;
            u.w = fmaxf(acc[i][q * 4 + 3], 0.f) + s3;
            orow[q] = u;
        }
    }
}

extern "C" void kernel_launch(void* const* d_in, const int* in_sizes, int n_in,
                              void* d_out, int out_size, void* d_ws, size_t ws_size,
                              hipStream_t stream) {
    const float* xyz   = (const float*)d_in[0];
    const float* pfeat = (const float*)d_in[1];
    const float* fclu  = (const float*)d_in[2];
    const int*   coors = (const int*)d_in[3];
    const float* rw0 = (const float*)d_in[4];
    const float* rg0 = (const float*)d_in[5];
    const float* rb0 = (const float*)d_in[6];
    const float* rw1 = (const float*)d_in[7];
    const float* rg1 = (const float*)d_in[8];
    const float* rb1 = (const float*)d_in[9];
    const float* vw0 = (const float*)d_in[10];
    const float* vg0 = (const float*)d_in[11];
    const float* vb0 = (const float*)d_in[12];
    const float* vw1 = (const float*)d_in[13];
    const float* vg1 = (const float*)d_in[14];
    const float* vb1 = (const float*)d_in[15];

    float* out = (float*)d_out;
    const int npts = in_sizes[3];
    const int blocks = (npts + 255) / 256;

    unsigned char* ws = (unsigned char*)d_ws;
    const size_t VMAX_B = (size_t)VVOX * 64 * sizeof(unsigned int);
    unsigned int* vmax = (unsigned int*)ws;
    unsigned int* cnt  = (unsigned int*)(ws + VMAX_B);
    unsigned int* perm = (unsigned int*)(ws + VMAX_B + (size_t)VVOX * 4);
    unsigned int* voxs = perm + npts;
    const size_t needed = VMAX_B + (size_t)VVOX * 4 + 2 * (size_t)npts * 4;

    // zero voxel-max buffer (identity for max over relu outputs; empty -> 0)
    hipMemsetAsync(vmax, 0, VMAX_B, stream);

    if (ws_size >= needed) {
        hipMemsetAsync(cnt, 0, (size_t)VVOX * 4, stream);
        hipLaunchKernelGGL(sir_hist, dim3(blocks), dim3(256), 0, stream,
                           coors, cnt, npts);
        hipLaunchKernelGGL(sir_scan, dim3(1), dim3(1024), 0, stream, cnt);
        hipLaunchKernelGGL(sir_permute, dim3(blocks), dim3(256), 0, stream,
                           coors, cnt, perm, voxs, npts);
        hipLaunchKernelGGL(HIP_KERNEL_NAME(sir_k1<false>), dim3(blocks), dim3(256), 0, stream,
                           xyz, pfeat, fclu, coors,
                           rw0, rg0, rb0, rw1, rg1, rb1,
                           vw0, vg0, vb0, vmax, out, npts);
        hipLaunchKernelGGL(sir_kmax, dim3(blocks), dim3(256), 0, stream,
                           out, perm, voxs, vmax, npts);
        hipLaunchKernelGGL(HIP_KERNEL_NAME(sir_k2<true>), dim3(blocks), dim3(256), 0, stream,
                           xyz, pfeat, coors, perm, voxs,
                           vw1, vg1, vb1, (const float*)vmax, out, npts);
    } else {
        // fallback: round-0 behavior (unsorted filtered atomics)
        hipLaunchKernelGGL(HIP_KERNEL_NAME(sir_k1<true>), dim3(blocks), dim3(256), 0, stream,
                           xyz, pfeat, fclu, coors,
                           rw0, rg0, rb0, rw1, rg1, rb1,
                           vw0, vg0, vb0, vmax, out, npts);
        hipLaunchKernelGGL(HIP_KERNEL_NAME(sir_k2<false>), dim3(blocks), dim3(256), 0, stream,
                           xyz, pfeat, coors, (const unsigned int*)nullptr,
                           (const unsigned int*)nullptr,
                           vw1, vg1, vb1, (const float*)vmax, out, npts);
    }
}